// Round 18
// baseline (433.393 us; speedup 1.0000x reference)
//
#include <hip/hip_runtime.h>
#include <hip/hip_bf16.h>

// AttributeGNN, bf16 MFMA, fp32 accumulate. B=16384, A=16, D=256.
// R18: R16 + LDS ping-pong ONLY (the zero-cost half of R17, unbundled from
// the fatal register double-buffer: R17's 2nd 64-VGPR B-set spilled ->
// FETCH 180->480MB, WRITE 368->565MB scratch traffic, fused 318->452us).
// Ping-pong X/Y: P1 EB->OB(G), P2 OB->EB(attr), P3 EB->(out,indiv), edge->OB.
// 3 syncthreads/iter (was 4); WRITEC overlapped with its GEMM phase.
// Single just-in-time B-set (64 VGPR) as in R16 -> no spill.

typedef __bf16 bf16_t;
typedef __bf16 bf16x4 __attribute__((ext_vector_type(4)));
typedef __bf16 bf16x8 __attribute__((ext_vector_type(8)));
typedef float f32x4 __attribute__((ext_vector_type(4)));

#define NB 16384
#define NA 16
#define ND 256
#define BM 64

// XOR swizzle for bf16 LDS tiles [*][256]: slot = chunk ^ (row&15), full
// permutation over 32 8-elem chunks -> conflict-free A-reads.
__device__ __forceinline__ int swz(int r, int c) {
    return r * 256 + (c ^ ((r & 15) << 3));
}

__device__ __forceinline__ bf16x8 cvt8(f32x4 a, f32x4 b) {
    bf16x8 r;
    r[0] = (bf16_t)a.x; r[1] = (bf16_t)a.y; r[2] = (bf16_t)a.z; r[3] = (bf16_t)a.w;
    r[4] = (bf16_t)b.x; r[5] = (bf16_t)b.y; r[6] = (bf16_t)b.z; r[7] = (bf16_t)b.w;
    return r;
}

// ---- W_agg [256][512] fp32 -> W1f / W2f fragment layout (bf16).
__global__ void prep_wfrag(const float* __restrict__ W,
                           bf16_t* __restrict__ W1f, bf16_t* __restrict__ W2f)
{
    int t = blockIdx.x * 256 + threadIdx.x;
    int lane = t & 63;
    int ks = (t >> 6) & 7;
    int nt = (t >> 9) & 15;
    int half = t >> 13;
    int row = nt * 16 + (lane & 15);
    int col = ks * 32 + (lane >> 4) * 8;
    const float* src = W + (size_t)row * 512 + half * 256 + col;
    bf16_t* dst = (half ? W2f : W1f) + ((nt * 8 + ks) * 64 + lane) * 8;
    bf16x8 v;
#pragma unroll
    for (int m = 0; m < 8; ++m) v[m] = (bf16_t)src[m];
    *(bf16x8*)dst = v;
}

// ---- P[a][i][j] fp32 -> fragment layout of P^T directly (one wave / frag).
__global__ void prep_pfrag2(const float* __restrict__ Pf, const float* __restrict__ Pb,
                            bf16_t* __restrict__ Pff, bf16_t* __restrict__ Pbf)
{
    int gw = (blockIdx.x * 256 + threadIdx.x) >> 6;   // 0..4095
    int lane = threadIdx.x & 63;
    int frag = gw & 127;
    int a = (gw >> 7) & 15;
    int mat = gw >> 11;
    int nt = frag >> 3, ks = frag & 7;
    const float* src = (mat ? Pb : Pf) + (size_t)a * 65536;
    bf16_t* dst = (mat ? Pbf : Pff) + (size_t)a * 65536 + ((size_t)frag * 64 + lane) * 8;
    int i0 = ks * 32 + (lane >> 4) * 8;
    int j = nt * 16 + (lane & 15);
    bf16x8 v;
#pragma unroll
    for (int m = 0; m < 8; ++m)
        v[m] = (bf16_t)src[(size_t)(i0 + m) * 256 + j];
    *(bf16x8*)dst = v;
}

// ---- fused main. 256 blocks x 512 thr, 1 block/CU, LDS 128KB.
__global__ __launch_bounds__(512, 2)
void fused_main(const float* __restrict__ img, const float* __restrict__ bias,
                const float* __restrict__ edge,
                const bf16_t* __restrict__ W1f, const bf16_t* __restrict__ W2f,
                const bf16_t* __restrict__ Pff, const bf16_t* __restrict__ Pbf,
                const float* __restrict__ sw, float* __restrict__ out)
{
    __shared__ bf16_t Xb[BM * 256];     // 32 KB ping
    __shared__ bf16_t Yb[BM * 256];     // 32 KB pong
    __shared__ float  Tl[BM * 256];     // 64 KB: T = img@W1^T + bias (a-invariant)

    const int tid = threadIdx.x;
    const int lane = tid & 63;
    const int wc = tid >> 6;            // 0..7: 32-col N-slice
    const int lr = lane & 15;
    const int lhi = lane >> 4;
    const int brow0 = blockIdx.x * BM;
    const int sr = tid >> 3;            // staging row 0..63
    const int scb = (tid & 7) * 32;     // staging col base (32 elems)

    bf16x8 B[2][8];                     // single B-set: 64 VGPR (as R16)
    f32x4 acc[2][2];
    f32x4 indiv[2][2][2];

#define LOADB(MAT) do {                                                       \
    const bf16_t* bp_ = (MAT) + (size_t)wc * 16 * 512 + lane * 8;             \
    _Pragma("unroll") for (int ni_ = 0; ni_ < 2; ++ni_)                       \
    _Pragma("unroll") for (int ks_ = 0; ks_ < 8; ++ks_)                       \
        B[ni_][ks_] = *(const bf16x8*)&bp_[(ni_ * 8 + ks_) * 512];            \
} while (0)

// One 32-row subtile GEMM into acc: A from LDS SRC (swizzled), B from regs.
#define SUBGEMM(SRC, IB) do {                                                 \
    _Pragma("unroll") for (int ks_ = 0; ks_ < 8; ++ks_) {                     \
        const int kc_ = ks_ * 32 + lhi * 8;                                   \
        bf16x8 af0_ = *(const bf16x8*)&(SRC)[swz((IB) * 32 + lr, kc_)];       \
        bf16x8 af1_ = *(const bf16x8*)&(SRC)[swz((IB) * 32 + 16 + lr, kc_)];  \
        acc[0][0] = __builtin_amdgcn_mfma_f32_16x16x32_bf16(af0_, B[0][ks_], acc[0][0], 0, 0, 0); \
        acc[1][0] = __builtin_amdgcn_mfma_f32_16x16x32_bf16(af1_, B[0][ks_], acc[1][0], 0, 0, 0); \
        acc[0][1] = __builtin_amdgcn_mfma_f32_16x16x32_bf16(af0_, B[1][ks_], acc[0][1], 0, 0, 0); \
        acc[1][1] = __builtin_amdgcn_mfma_f32_16x16x32_bf16(af1_, B[1][ks_], acc[1][1], 0, 0, 0); \
    }                                                                         \
} while (0)

// C-scatter of acc to LDS (bf16, swizzled), subtile IB.
#define WRITEC(DST, IB) do {                                                  \
    _Pragma("unroll") for (int mi_ = 0; mi_ < 2; ++mi_)                       \
    _Pragma("unroll") for (int ni_ = 0; ni_ < 2; ++ni_)                       \
    _Pragma("unroll") for (int j_ = 0; j_ < 4; ++j_)                          \
        (DST)[swz((IB) * 32 + mi_ * 16 + lhi * 4 + j_, wc * 32 + ni_ * 16 + lr)] = (bf16_t)acc[mi_][ni_][j_]; \
} while (0)

#define ACC_FROM_T(IB) do {                                                   \
    _Pragma("unroll") for (int mi_ = 0; mi_ < 2; ++mi_)                       \
    _Pragma("unroll") for (int ni_ = 0; ni_ < 2; ++ni_)                       \
    _Pragma("unroll") for (int j_ = 0; j_ < 4; ++j_)                          \
        acc[mi_][ni_][j_] = Tl[((IB) * 32 + mi_ * 16 + lhi * 4 + j_) * 256 + wc * 32 + ni_ * 16 + lr]; \
} while (0)

#define ACC_ZERO() do {                                                       \
    _Pragma("unroll") for (int mi_ = 0; mi_ < 2; ++mi_)                       \
    _Pragma("unroll") for (int ni_ = 0; ni_ < 2; ++ni_)                       \
        acc[mi_][ni_] = (f32x4){0.f, 0.f, 0.f, 0.f};                          \
} while (0)

// Stage edge[brow0+sr][A_][scb..+31] (fp32, 128B/thread contiguous) -> DST bf16 swz.
#define STAGE_EDGE_TO(DST, A_) do {                                           \
    const float* ep_ = edge + ((size_t)(brow0 + sr) * NA + (A_)) * ND + scb;  \
    f32x4 w0 = *(const f32x4*)(ep_ + 0),  w1 = *(const f32x4*)(ep_ + 4);      \
    f32x4 w2 = *(const f32x4*)(ep_ + 8),  w3 = *(const f32x4*)(ep_ + 12);     \
    f32x4 w4 = *(const f32x4*)(ep_ + 16), w5 = *(const f32x4*)(ep_ + 20);     \
    f32x4 w6 = *(const f32x4*)(ep_ + 24), w7 = *(const f32x4*)(ep_ + 28);     \
    *(bf16x8*)&(DST)[swz(sr, scb + 0)]  = cvt8(w0, w1);                       \
    *(bf16x8*)&(DST)[swz(sr, scb + 8)]  = cvt8(w2, w3);                       \
    *(bf16x8*)&(DST)[swz(sr, scb + 16)] = cvt8(w4, w5);                       \
    *(bf16x8*)&(DST)[swz(sr, scb + 24)] = cvt8(w6, w7);                       \
} while (0)

// Full-line fp32 attr store for edge-type A_ from swizzled bf16 buffer SRCBUF.
#define ATTR_STORE(SRCBUF, A_) do {                                           \
    float* op_ = out + (size_t)(brow0 + sr) * (NA * ND) + (size_t)(A_) * ND + scb; \
    _Pragma("unroll") for (int q_ = 0; q_ < 4; ++q_) {                        \
        bf16x8 v_ = *(const bf16x8*)&(SRCBUF)[swz(sr, scb + q_ * 8)];         \
        f32x4 lo_ = {(float)v_[0], (float)v_[1], (float)v_[2], (float)v_[3]}; \
        f32x4 hi_ = {(float)v_[4], (float)v_[5], (float)v_[6], (float)v_[7]}; \
        *(f32x4*)(op_ + q_ * 8) = lo_;                                        \
        *(f32x4*)(op_ + q_ * 8 + 4) = hi_;                                    \
    }                                                                         \
} while (0)

// One a-iteration, ping-pong. EB holds edge(A_); OB is scratch.
// P1: G -> OB. P2: attr -> EB. P3: stores+GEMM3 from EB; edge(A_+1) -> OB.
#define ITER(A_, EB, OB) do {                                                 \
    LOADB(W2f);                                                               \
    ACC_FROM_T(0); SUBGEMM(EB, 0); WRITEC(OB, 0);                             \
    ACC_FROM_T(1); SUBGEMM(EB, 1); WRITEC(OB, 1);                             \
    __syncthreads();      /* G visible; EB reads done */                      \
    LOADB(Pff + (size_t)(A_) * 65536);                                        \
    ACC_ZERO(); SUBGEMM(OB, 0); WRITEC(EB, 0);                                \
    ACC_ZERO(); SUBGEMM(OB, 1); WRITEC(EB, 1);                                \
    __syncthreads();      /* attr visible in EB; OB reads done */             \
    LOADB(Pbf + (size_t)(A_) * 65536);                                        \
    ATTR_STORE(EB, A_);                                                       \
    ACC_ZERO(); SUBGEMM(EB, 0);                                               \
    {   const float swa_ = sw[A_];                                            \
        _Pragma("unroll") for (int mi_ = 0; mi_ < 2; ++mi_)                   \
        _Pragma("unroll") for (int ni_ = 0; ni_ < 2; ++ni_)                   \
        _Pragma("unroll") for (int j_ = 0; j_ < 4; ++j_)                      \
            indiv[0][mi_][ni_][j_] += fmaxf(acc[mi_][ni_][j_], 0.f) * swa_;   \
    }                                                                         \
    ACC_ZERO(); SUBGEMM(EB, 1);                                               \
    {   const float swa_ = sw[A_];                                            \
        _Pragma("unroll") for (int mi_ = 0; mi_ < 2; ++mi_)                   \
        _Pragma("unroll") for (int ni_ = 0; ni_ < 2; ++ni_)                   \
        _Pragma("unroll") for (int j_ = 0; j_ < 4; ++j_)                      \
            indiv[1][mi_][ni_][j_] += fmaxf(acc[mi_][ni_][j_], 0.f) * swa_;   \
    }                                                                         \
    if ((A_) + 1 < NA) STAGE_EDGE_TO(OB, (A_) + 1);                           \
    __syncthreads();      /* edge(A_+1) visible; EB reads done */             \
} while (0)

    // ---- prologue: stage img -> Xb (bf16 swz)
    {
        const float* ip = img + (size_t)(brow0 + sr) * ND + scb;
#pragma unroll
        for (int q = 0; q < 4; ++q) {
            f32x4 v0 = *(const f32x4*)(ip + q * 8);
            f32x4 v1 = *(const f32x4*)(ip + q * 8 + 4);
            *(bf16x8*)&Xb[swz(sr, scb + q * 8)] = cvt8(v0, v1);
        }
    }
    __syncthreads();

    // ---- T = img @ W1^T + bias -> Tl
    LOADB(W1f);
    {
        float bz0 = bias[wc * 32 + lr];
        float bz1 = bias[wc * 32 + 16 + lr];
#pragma unroll
        for (int ib = 0; ib < 2; ++ib) {
            acc[0][0] = (f32x4){bz0, bz0, bz0, bz0};
            acc[1][0] = (f32x4){bz0, bz0, bz0, bz0};
            acc[0][1] = (f32x4){bz1, bz1, bz1, bz1};
            acc[1][1] = (f32x4){bz1, bz1, bz1, bz1};
            if (ib == 0) { SUBGEMM(Xb, 0); }
            else         { SUBGEMM(Xb, 1); }
#pragma unroll
            for (int mi = 0; mi < 2; ++mi)
#pragma unroll
                for (int ni = 0; ni < 2; ++ni)
#pragma unroll
                    for (int j = 0; j < 4; ++j)
                        Tl[(ib * 32 + mi * 16 + lhi * 4 + j) * 256 + wc * 32 + ni * 16 + lr] = acc[mi][ni][j];
        }
    }
    __syncthreads();                    // Tl visible; Xb (img) free

    // ---- edge(0) -> Xb
    STAGE_EDGE_TO(Xb, 0);
    __syncthreads();

#pragma unroll
    for (int i = 0; i < 2; ++i)
#pragma unroll
        for (int mi = 0; mi < 2; ++mi)
#pragma unroll
            for (int ni = 0; ni < 2; ++ni)
                indiv[i][mi][ni] = (f32x4){0.f, 0.f, 0.f, 0.f};

    // ---- a-loop: 8 double-iterations with static buffer rotation
    for (int ah = 0; ah < 8; ++ah) {
        const int a0 = ah * 2;
        ITER(a0,     Xb, Yb);
        ITER(a0 + 1, Yb, Xb);
    }

    // ---- individual_embeddings
#pragma unroll
    for (int i = 0; i < 2; ++i)
#pragma unroll
        for (int mi = 0; mi < 2; ++mi)
#pragma unroll
            for (int ni = 0; ni < 2; ++ni)
#pragma unroll
                for (int j = 0; j < 4; ++j) {
                    int r = i * 32 + mi * 16 + lhi * 4 + j;
                    int c = wc * 32 + ni * 16 + lr;
                    out[(size_t)NB * NA * ND + (size_t)(brow0 + r) * ND + c] = indiv[i][mi][ni][j];
                }
#undef LOADB
#undef SUBGEMM
#undef WRITEC
#undef ACC_FROM_T
#undef ACC_ZERO
#undef STAGE_EDGE_TO
#undef ATTR_STORE
#undef ITER
}

extern "C" void kernel_launch(void* const* d_in, const int* in_sizes, int n_in,
                              void* d_out, int out_size, void* d_ws, size_t ws_size,
                              hipStream_t stream)
{
    const float* img  = (const float*)d_in[0];
    const float* edge = (const float*)d_in[1];
    const float* Wagg = (const float*)d_in[2];
    const float* bagg = (const float*)d_in[3];
    const float* Pf   = (const float*)d_in[4];
    const float* Pb   = (const float*)d_in[5];
    const float* sw   = (const float*)d_in[6];
    float* out = (float*)d_out;

    char* ws = (char*)d_ws;
    bf16_t* W1f = (bf16_t*)(ws);                   // 128 KB fragment layout
    bf16_t* W2f = (bf16_t*)(ws + 131072);          // 128 KB
    bf16_t* Pff = (bf16_t*)(ws + 262144);          // 2 MB
    bf16_t* Pbf = (bf16_t*)(ws + 2359296);         // 2 MB

    prep_wfrag<<<64, 256, 0, stream>>>(Wagg, W1f, W2f);
    prep_pfrag2<<<1024, 256, 0, stream>>>(Pf, Pb, Pff, Pbf);
    fused_main<<<NB / BM, 512, 0, stream>>>(img, bagg, edge, W1f, W2f, Pff, Pbf, sw, out);
}

// Round 19
// 304.980 us; speedup vs baseline: 1.4211x; 1.4211x over previous
//
#include <hip/hip_runtime.h>
#include <hip/hip_bf16.h>

// AttributeGNN, bf16 MFMA, fp32 accumulate. B=16384, A=16, D=256.
// R19: RESTORE R16 verbatim - the verified best (304us total; fused 318us).
// R17 (reg double-buffer) and R18 (ping-pong + unified acc) both regressed:
// R17 spilled (2nd 64-VGPR B-set); R18 lost inter-subtile MFMA ILP (serial
// acc chains) + spilled. R16's structure: B-in-registers M-subtiled core
// (weight traffic 1.57GB), dual-acc ILP, 4 syncthreads/iter, edge read
// direct from [b][a][d] fp32, prep chain fused to 2 tiny kernels.

typedef __bf16 bf16_t;
typedef __bf16 bf16x4 __attribute__((ext_vector_type(4)));
typedef __bf16 bf16x8 __attribute__((ext_vector_type(8)));
typedef float f32x4 __attribute__((ext_vector_type(4)));

#define NB 16384
#define NA 16
#define ND 256
#define BM 64

// XOR swizzle for bf16 LDS tiles [*][256]: slot = chunk ^ (row&15), full
// permutation over 32 8-elem chunks -> conflict-free A-reads.
__device__ __forceinline__ int swz(int r, int c) {
    return r * 256 + (c ^ ((r & 15) << 3));
}

__device__ __forceinline__ bf16x8 cvt8(f32x4 a, f32x4 b) {
    bf16x8 r;
    r[0] = (bf16_t)a.x; r[1] = (bf16_t)a.y; r[2] = (bf16_t)a.z; r[3] = (bf16_t)a.w;
    r[4] = (bf16_t)b.x; r[5] = (bf16_t)b.y; r[6] = (bf16_t)b.z; r[7] = (bf16_t)b.w;
    return r;
}

// ---- W_agg [256][512] fp32 -> W1f / W2f fragment layout (bf16).
__global__ void prep_wfrag(const float* __restrict__ W,
                           bf16_t* __restrict__ W1f, bf16_t* __restrict__ W2f)
{
    int t = blockIdx.x * 256 + threadIdx.x;
    int lane = t & 63;
    int ks = (t >> 6) & 7;
    int nt = (t >> 9) & 15;
    int half = t >> 13;
    int row = nt * 16 + (lane & 15);
    int col = ks * 32 + (lane >> 4) * 8;
    const float* src = W + (size_t)row * 512 + half * 256 + col;
    bf16_t* dst = (half ? W2f : W1f) + ((nt * 8 + ks) * 64 + lane) * 8;
    bf16x8 v;
#pragma unroll
    for (int m = 0; m < 8; ++m) v[m] = (bf16_t)src[m];
    *(bf16x8*)dst = v;
}

// ---- P[a][i][j] fp32 -> fragment layout of P^T directly (one wave / frag).
// Fragment f=(nt*8+ks), lane l, elem m = P^T[nt*16+(l&15)][ks*32+(l>>4)*8+m]
//                                      = P[ks*32+(l>>4)*8+m][nt*16+(l&15)].
__global__ void prep_pfrag2(const float* __restrict__ Pf, const float* __restrict__ Pb,
                            bf16_t* __restrict__ Pff, bf16_t* __restrict__ Pbf)
{
    int gw = (blockIdx.x * 256 + threadIdx.x) >> 6;   // 0..4095
    int lane = threadIdx.x & 63;
    int frag = gw & 127;
    int a = (gw >> 7) & 15;
    int mat = gw >> 11;
    int nt = frag >> 3, ks = frag & 7;
    const float* src = (mat ? Pb : Pf) + (size_t)a * 65536;
    bf16_t* dst = (mat ? Pbf : Pff) + (size_t)a * 65536 + ((size_t)frag * 64 + lane) * 8;
    int i0 = ks * 32 + (lane >> 4) * 8;
    int j = nt * 16 + (lane & 15);
    bf16x8 v;
#pragma unroll
    for (int m = 0; m < 8; ++m)
        v[m] = (bf16_t)src[(size_t)(i0 + m) * 256 + j];
    *(bf16x8*)dst = v;
}

// ---- fused main. 256 blocks x 512 thr, 1 block/CU, LDS 128KB.
__global__ __launch_bounds__(512, 2)
void fused_main(const float* __restrict__ img, const float* __restrict__ bias,
                const float* __restrict__ edge,
                const bf16_t* __restrict__ W1f, const bf16_t* __restrict__ W2f,
                const bf16_t* __restrict__ Pff, const bf16_t* __restrict__ Pbf,
                const float* __restrict__ sw, float* __restrict__ out)
{
    __shared__ bf16_t EG[BM * 256];     // 32 KB: edge tile, then G (agg), alternating
    __shared__ bf16_t Rl[BM * 256];     // 32 KB: attr bf16
    __shared__ float  Tl[BM * 256];     // 64 KB: T = img@W1^T + bias (a-invariant)

    const int tid = threadIdx.x;
    const int lane = tid & 63;
    const int wc = tid >> 6;            // 0..7: 32-col N-slice
    const int lr = lane & 15;
    const int lhi = lane >> 4;
    const int brow0 = blockIdx.x * BM;
    const int sr = tid >> 3;            // staging row 0..63
    const int scb = (tid & 7) * 32;     // staging col base (32 elems)

    bf16x8 B[2][8];                     // wave's B-slice: 16 frags = 64 VGPR

#define LOADB(MAT) do {                                                       \
    const bf16_t* bp_ = (MAT) + (size_t)wc * 16 * 512 + lane * 8;             \
    _Pragma("unroll") for (int ni_ = 0; ni_ < 2; ++ni_)                       \
    _Pragma("unroll") for (int ks_ = 0; ks_ < 8; ++ks_)                       \
        B[ni_][ks_] = *(const bf16x8*)&bp_[(ni_ * 8 + ks_) * 512];            \
} while (0)

// One 32-row subtile GEMM: A from LDS SRC (swizzled), B from regs. Zero vmem.
#define SUBGEMM(SRC, IB, ACC) do {                                            \
    _Pragma("unroll") for (int ks_ = 0; ks_ < 8; ++ks_) {                     \
        const int kc_ = ks_ * 32 + lhi * 8;                                   \
        bf16x8 af0_ = *(const bf16x8*)&(SRC)[swz((IB) * 32 + lr, kc_)];       \
        bf16x8 af1_ = *(const bf16x8*)&(SRC)[swz((IB) * 32 + 16 + lr, kc_)];  \
        ACC[0][0] = __builtin_amdgcn_mfma_f32_16x16x32_bf16(af0_, B[0][ks_], ACC[0][0], 0, 0, 0); \
        ACC[1][0] = __builtin_amdgcn_mfma_f32_16x16x32_bf16(af1_, B[0][ks_], ACC[1][0], 0, 0, 0); \
        ACC[0][1] = __builtin_amdgcn_mfma_f32_16x16x32_bf16(af0_, B[1][ks_], ACC[0][1], 0, 0, 0); \
        ACC[1][1] = __builtin_amdgcn_mfma_f32_16x16x32_bf16(af1_, B[1][ks_], ACC[1][1], 0, 0, 0); \
    }                                                                         \
} while (0)

// C-scatter to LDS (bf16, swizzled), subtile IB.
#define WRITEC(DST, IB, ACC) do {                                             \
    _Pragma("unroll") for (int mi_ = 0; mi_ < 2; ++mi_)                       \
    _Pragma("unroll") for (int ni_ = 0; ni_ < 2; ++ni_)                       \
    _Pragma("unroll") for (int j_ = 0; j_ < 4; ++j_)                          \
        (DST)[swz((IB) * 32 + mi_ * 16 + lhi * 4 + j_, wc * 32 + ni_ * 16 + lr)] = (bf16_t)ACC[mi_][ni_][j_]; \
} while (0)

// Stage edge[brow0+sr][A_][scb..scb+31] (fp32, 128B/thread contiguous) -> EG bf16 swz.
#define STAGE_EDGE(A_) do {                                                   \
    const float* ep_ = edge + ((size_t)(brow0 + sr) * NA + (A_)) * ND + scb;  \
    f32x4 w0 = *(const f32x4*)(ep_ + 0),  w1 = *(const f32x4*)(ep_ + 4);      \
    f32x4 w2 = *(const f32x4*)(ep_ + 8),  w3 = *(const f32x4*)(ep_ + 12);     \
    f32x4 w4 = *(const f32x4*)(ep_ + 16), w5 = *(const f32x4*)(ep_ + 20);     \
    f32x4 w6 = *(const f32x4*)(ep_ + 24), w7 = *(const f32x4*)(ep_ + 28);     \
    *(bf16x8*)&EG[swz(sr, scb + 0)]  = cvt8(w0, w1);                          \
    *(bf16x8*)&EG[swz(sr, scb + 8)]  = cvt8(w2, w3);                          \
    *(bf16x8*)&EG[swz(sr, scb + 16)] = cvt8(w4, w5);                          \
    *(bf16x8*)&EG[swz(sr, scb + 24)] = cvt8(w6, w7);                          \
} while (0)

    // ---- prologue: stage img -> EG (bf16 swz)
    {
        const float* ip = img + (size_t)(brow0 + sr) * ND + scb;
#pragma unroll
        for (int q = 0; q < 4; ++q) {
            f32x4 v0 = *(const f32x4*)(ip + q * 8);
            f32x4 v1 = *(const f32x4*)(ip + q * 8 + 4);
            *(bf16x8*)&EG[swz(sr, scb + q * 8)] = cvt8(v0, v1);
        }
    }
    __syncthreads();

    // ---- T = img @ W1^T + bias -> Tl (fp32 LDS)
    f32x4 acc0[2][2], acc1[2][2];
    {
        LOADB(W1f);
#pragma unroll
        for (int ni = 0; ni < 2; ++ni) {
            float bz = bias[wc * 32 + ni * 16 + lr];
            acc0[0][ni] = (f32x4){bz, bz, bz, bz}; acc0[1][ni] = (f32x4){bz, bz, bz, bz};
            acc1[0][ni] = (f32x4){bz, bz, bz, bz}; acc1[1][ni] = (f32x4){bz, bz, bz, bz};
        }
        SUBGEMM(EG, 0, acc0);
        SUBGEMM(EG, 1, acc1);
#pragma unroll
        for (int mi = 0; mi < 2; ++mi)
#pragma unroll
            for (int ni = 0; ni < 2; ++ni)
#pragma unroll
                for (int j = 0; j < 4; ++j) {
                    int c = wc * 32 + ni * 16 + lr;
                    Tl[(mi * 16 + lhi * 4 + j) * 256 + c] = acc0[mi][ni][j];
                    Tl[(32 + mi * 16 + lhi * 4 + j) * 256 + c] = acc1[mi][ni][j];
                }
    }
    __syncthreads();

    // ---- stage edge(a=0) -> EG (direct from [b][a][d] fp32)
    STAGE_EDGE(0);
    __syncthreads();

    f32x4 indiv[2][2][2];
#pragma unroll
    for (int i = 0; i < 2; ++i)
#pragma unroll
        for (int mi = 0; mi < 2; ++mi)
#pragma unroll
            for (int ni = 0; ni < 2; ++ni)
                indiv[i][mi][ni] = (f32x4){0.f, 0.f, 0.f, 0.f};

    for (int a = 0; a < NA; ++a) {
        // ---- P1: agg = T + edge @ W2^T (B=W2 regs, A=EG, C->EG as G)
        LOADB(W2f);
#pragma unroll
        for (int mi = 0; mi < 2; ++mi)
#pragma unroll
            for (int ni = 0; ni < 2; ++ni)
#pragma unroll
                for (int j = 0; j < 4; ++j) {
                    int c = wc * 32 + ni * 16 + lr;
                    acc0[mi][ni][j] = Tl[(mi * 16 + lhi * 4 + j) * 256 + c];
                    acc1[mi][ni][j] = Tl[(32 + mi * 16 + lhi * 4 + j) * 256 + c];
                }
        SUBGEMM(EG, 0, acc0);
        SUBGEMM(EG, 1, acc1);
        __syncthreads();                // all EG (edge) reads complete block-wide
        WRITEC(EG, 0, acc0);            // overwrite EG with G
        WRITEC(EG, 1, acc1);
        __syncthreads();                // G visible

        // ---- P2: attr = G @ Pf[a] -> Rl
        LOADB(Pff + (size_t)a * 65536);
#pragma unroll
        for (int mi = 0; mi < 2; ++mi)
#pragma unroll
            for (int ni = 0; ni < 2; ++ni) {
                acc0[mi][ni] = (f32x4){0.f, 0.f, 0.f, 0.f};
                acc1[mi][ni] = (f32x4){0.f, 0.f, 0.f, 0.f};
            }
        SUBGEMM(EG, 0, acc0);
        SUBGEMM(EG, 1, acc1);
        WRITEC(Rl, 0, acc0);
        WRITEC(Rl, 1, acc1);
        __syncthreads();                // Rl visible; EG reads complete

        // ---- P3: Pb loads; attr stores from Rl; GEMM3 -> indiv; edge(a+1) -> EG
        LOADB(Pbf + (size_t)a * 65536);
        {   // full-line fp32 attr stores (read Rl, convert)
            float* op = out + (size_t)(brow0 + sr) * (NA * ND) + (size_t)a * ND + scb;
#pragma unroll
            for (int q = 0; q < 4; ++q) {
                bf16x8 v = *(const bf16x8*)&Rl[swz(sr, scb + q * 8)];
                f32x4 lo = {(float)v[0], (float)v[1], (float)v[2], (float)v[3]};
                f32x4 hi = {(float)v[4], (float)v[5], (float)v[6], (float)v[7]};
                *(f32x4*)(op + q * 8) = lo;
                *(f32x4*)(op + q * 8 + 4) = hi;
            }
        }
#pragma unroll
        for (int mi = 0; mi < 2; ++mi)
#pragma unroll
            for (int ni = 0; ni < 2; ++ni) {
                acc0[mi][ni] = (f32x4){0.f, 0.f, 0.f, 0.f};
                acc1[mi][ni] = (f32x4){0.f, 0.f, 0.f, 0.f};
            }
        SUBGEMM(Rl, 0, acc0);
        SUBGEMM(Rl, 1, acc1);
        const float swa = sw[a];
#pragma unroll
        for (int mi = 0; mi < 2; ++mi)
#pragma unroll
            for (int ni = 0; ni < 2; ++ni)
#pragma unroll
                for (int j = 0; j < 4; ++j) {
                    indiv[0][mi][ni][j] += fmaxf(acc0[mi][ni][j], 0.f) * swa;
                    indiv[1][mi][ni][j] += fmaxf(acc1[mi][ni][j], 0.f) * swa;
                }
        if (a + 1 < NA) {               // stage edge(a+1) into EG (G consumed)
            STAGE_EDGE(a + 1);
        }
        __syncthreads();                // edge(a+1) visible; Rl reads complete
    }

    // ---- individual_embeddings
#pragma unroll
    for (int i = 0; i < 2; ++i)
#pragma unroll
        for (int mi = 0; mi < 2; ++mi)
#pragma unroll
            for (int ni = 0; ni < 2; ++ni)
#pragma unroll
                for (int j = 0; j < 4; ++j) {
                    int r = i * 32 + mi * 16 + lhi * 4 + j;
                    int c = wc * 32 + ni * 16 + lr;
                    out[(size_t)NB * NA * ND + (size_t)(brow0 + r) * ND + c] = indiv[i][mi][ni][j];
                }
#undef LOADB
#undef SUBGEMM
#undef WRITEC
#undef STAGE_EDGE
}

extern "C" void kernel_launch(void* const* d_in, const int* in_sizes, int n_in,
                              void* d_out, int out_size, void* d_ws, size_t ws_size,
                              hipStream_t stream)
{
    const float* img  = (const float*)d_in[0];
    const float* edge = (const float*)d_in[1];
    const float* Wagg = (const float*)d_in[2];
    const float* bagg = (const float*)d_in[3];
    const float* Pf   = (const float*)d_in[4];
    const float* Pb   = (const float*)d_in[5];
    const float* sw   = (const float*)d_in[6];
    float* out = (float*)d_out;

    char* ws = (char*)d_ws;
    bf16_t* W1f = (bf16_t*)(ws);                   // 128 KB fragment layout
    bf16_t* W2f = (bf16_t*)(ws + 131072);          // 128 KB
    bf16_t* Pff = (bf16_t*)(ws + 262144);          // 2 MB
    bf16_t* Pbf = (bf16_t*)(ws + 2359296);         // 2 MB

    prep_wfrag<<<64, 256, 0, stream>>>(Wagg, W1f, W2f);
    prep_pfrag2<<<1024, 256, 0, stream>>>(Pf, Pb, Pff, Pbf);
    fused_main<<<NB / BM, 512, 0, stream>>>(img, bagg, edge, W1f, W2f, Pff, Pbf, sw, out);
}